// Round 1
// baseline (145.841 us; speedup 1.0000x reference)
//
#include <hip/hip_runtime.h>

// Problem constants (from setup_inputs): N=4096, C=64, A=256
#define N_ROWS 4096
#define C_CLS  64
#define A_DIM  256
#define BK     32          // K-chunk (over b) per block in kernel A
#define KCHUNK (A_DIM / BK) // 8

// ---------------------------------------------------------------------------
// Kernel A: S[y][c] = (w_c - w_y)^T CV[y] (w_c - w_y)   (no Lambda factor yet)
// Decomposed: T[c][a] = sum_b D[c][b] * CV[y][a][b]  (CV symmetric -> read rows)
//             S[c]    = sum_a D[c][a] * T[c][a]
// Partial over b-chunks is valid since S is linear in T. grid = 64*KCHUNK.
// ---------------------------------------------------------------------------
__global__ __launch_bounds__(256) void qform_kernel(
    const float* __restrict__ W,    // [C][A]
    const float* __restrict__ CV,   // [C][A][A]
    float* __restrict__ S)          // [C][C], pre-zeroed
{
    __shared__ float Vt[BK][A_DIM];   // 32 KB : Vt[k][a] = CV[y][kb+k][a]
    __shared__ float Dt[BK][C_CLS];   //  8 KB : Dt[k][c] = W[c][kb+k]-W[y][kb+k]
    __shared__ float Sred[C_CLS];

    const int t  = threadIdx.x;
    const int y  = blockIdx.x >> 3;          // blockIdx / KCHUNK
    const int kb = (blockIdx.x & 7) * BK;    // b-range start

    // ---- stage Vt: rows kb..kb+BK-1 of CV[y] (contiguous 32 KB, coalesced) ----
    {
        const float4* src = (const float4*)(CV + ((size_t)y * A_DIM * A_DIM
                                                  + (size_t)kb * A_DIM));
        float4* vdst = (float4*)&Vt[0][0];
        #pragma unroll
        for (int i = 0; i < (BK * A_DIM / 4) / 256; ++i)
            vdst[t + i * 256] = src[t + i * 256];
    }

    // ---- stage Dt (transposed diff chunk) ----
    {
        const int kq    = (t & 7) * 4;   // k = kq..kq+3
        const int chalf = t >> 3;        // 0..31
        const float4 wy = *(const float4*)(W + y * A_DIM + kb + kq);
        #pragma unroll
        for (int cc = 0; cc < 2; ++cc) {
            const int c = chalf + cc * 32;
            const float4 wc = *(const float4*)(W + c * A_DIM + kb + kq);
            Dt[kq + 0][c] = wc.x - wy.x;
            Dt[kq + 1][c] = wc.y - wy.y;
            Dt[kq + 2][c] = wc.z - wy.z;
            Dt[kq + 3][c] = wc.w - wy.w;
        }
    }
    if (t < C_CLS) Sred[t] = 0.0f;
    __syncthreads();

    // ---- 8x8 register tile of T: c0 = (t%8)*8 covers 64 c, a0 = (t/8)*8 covers 256 a
    const int c0 = (t & 7) * 8;
    const int a0 = (t >> 3) * 8;
    float acc[8][8];
    #pragma unroll
    for (int i = 0; i < 8; ++i)
        #pragma unroll
        for (int j = 0; j < 8; ++j) acc[i][j] = 0.0f;

    #pragma unroll 2
    for (int k = 0; k < BK; ++k) {
        const float4 a_lo = *(const float4*)&Vt[k][a0];
        const float4 a_hi = *(const float4*)&Vt[k][a0 + 4];
        const float4 d_lo = *(const float4*)&Dt[k][c0];
        const float4 d_hi = *(const float4*)&Dt[k][c0 + 4];
        const float af[8] = {a_lo.x, a_lo.y, a_lo.z, a_lo.w,
                             a_hi.x, a_hi.y, a_hi.z, a_hi.w};
        const float df[8] = {d_lo.x, d_lo.y, d_lo.z, d_lo.w,
                             d_hi.x, d_hi.y, d_hi.z, d_hi.w};
        #pragma unroll
        for (int i = 0; i < 8; ++i)
            #pragma unroll
            for (int j = 0; j < 8; ++j)
                acc[i][j] += df[i] * af[j];
    }

    // ---- fused epilogue: s_i = sum_j acc[i][j] * (W[c0+i][a0+j] - W[y][a0+j]) ----
    {
        const float4 wy_lo = *(const float4*)(W + y * A_DIM + a0);
        const float4 wy_hi = *(const float4*)(W + y * A_DIM + a0 + 4);
        const float wyv[8] = {wy_lo.x, wy_lo.y, wy_lo.z, wy_lo.w,
                              wy_hi.x, wy_hi.y, wy_hi.z, wy_hi.w};
        #pragma unroll
        for (int i = 0; i < 8; ++i) {
            const int c = c0 + i;
            const float4 wc_lo = *(const float4*)(W + c * A_DIM + a0);
            const float4 wc_hi = *(const float4*)(W + c * A_DIM + a0 + 4);
            const float wcv[8] = {wc_lo.x, wc_lo.y, wc_lo.z, wc_lo.w,
                                  wc_hi.x, wc_hi.y, wc_hi.z, wc_hi.w};
            float s = 0.0f;
            #pragma unroll
            for (int j = 0; j < 8; ++j)
                s += acc[i][j] * (wcv[j] - wyv[j]);
            atomicAdd(&Sred[c], s);   // LDS atomic (ds_add_f32)
        }
    }
    __syncthreads();
    if (t < C_CLS) atomicAdd(&S[y * C_CLS + t], Sred[t]);
}

// ---------------------------------------------------------------------------
// Kernel B: per-row softmax cross-entropy on aug = pred + 0.5*Lambda*S[y].
// One wave (64 lanes) per row; lane == class index. 4 rows per 256-thr block.
// ---------------------------------------------------------------------------
__global__ __launch_bounds__(256) void loss_kernel(
    const float* __restrict__ pred,    // [N][C]
    const int*   __restrict__ labels,  // [N]
    const float* __restrict__ lambda_p,
    const float* __restrict__ S,       // [C][C]
    float* __restrict__ out)           // [1], pre-zeroed
{
    const int t    = threadIdx.x;
    const int lane = t & 63;
    const int n    = blockIdx.x * 4 + (t >> 6);
    const int y    = labels[n];
    const float lam = 0.5f * lambda_p[0];

    float logit = pred[n * C_CLS + lane] + lam * S[y * C_CLS + lane];

    float m = logit;
    #pragma unroll
    for (int off = 32; off > 0; off >>= 1)
        m = fmaxf(m, __shfl_xor(m, off, 64));
    float e = __expf(logit - m);
    float ssum = e;
    #pragma unroll
    for (int off = 32; off > 0; off >>= 1)
        ssum += __shfl_xor(ssum, off, 64);
    const float ly = __shfl(logit, y, 64);

    if (lane == 0) {
        const float nll = logf(ssum) + m - ly;
        atomicAdd(out, nll * (1.0f / (float)N_ROWS));
    }
}

// ---------------------------------------------------------------------------
extern "C" void kernel_launch(void* const* d_in, const int* in_sizes, int n_in,
                              void* d_out, int out_size, void* d_ws, size_t ws_size,
                              hipStream_t stream) {
    (void)in_sizes; (void)n_in; (void)out_size; (void)ws_size;
    const float* W      = (const float*)d_in[0];   // fc_weight [64][256]
    // d_in[1] = features (unused by the reference computation)
    const float* pred   = (const float*)d_in[2];   // [4096][64]
    const int*   labels = (const int*)d_in[3];     // [4096]
    const float* lam    = (const float*)d_in[4];   // scalar
    const float* CV     = (const float*)d_in[5];   // [64][256][256]
    float* out = (float*)d_out;
    float* S   = (float*)d_ws;                     // [64][64] scratch

    hipMemsetAsync(S, 0, C_CLS * C_CLS * sizeof(float), stream);
    hipMemsetAsync(out, 0, sizeof(float), stream);
    qform_kernel<<<dim3(C_CLS * KCHUNK), dim3(256), 0, stream>>>(W, CV, S);
    loss_kernel<<<dim3(N_ROWS / 4), dim3(256), 0, stream>>>(pred, labels, lam, S, out);
}

// Round 2
// 88.411 us; speedup vs baseline: 1.6496x; 1.6496x over previous
//
#include <hip/hip_runtime.h>

// Problem constants (from setup_inputs): N=4096, C=64, A=256
#define N_ROWS 4096
#define C_CLS  64
#define A_DIM  256
#define BK     32           // K-chunk (over b) per block in kernel A
#define KCHUNK (A_DIM / BK) // 8
#define LOSS_BLOCKS 256     // kernel B blocks (4 waves each, 4 rows/wave)

// ---------------------------------------------------------------------------
// Kernel A: Spart[chunk][y][c] = partial over b-chunk of (w_c-w_y)^T CV[y] (w_c-w_y)
// T[c][a] = sum_b D[c][b] * CV[y][b][a]  (CV symmetric -> row reads)
// S[c]    = sum_a D[c][a] * T[c][a]; linear in T so per-chunk partials sum.
// grid = 64*KCHUNK = 512 blocks (2 blocks/CU on 256 CUs).
// ---------------------------------------------------------------------------
__global__ __launch_bounds__(256) void qform_kernel(
    const float* __restrict__ W,      // [C][A]
    const float* __restrict__ CV,     // [C][A][A]
    float* __restrict__ Spart)        // [KCHUNK][C][C]
{
    __shared__ float Vt[BK][A_DIM];   // 32 KB : Vt[k][a] = CV[y][kb+k][a]
    __shared__ float Dt[BK][C_CLS];   //  8 KB : Dt[k][c] = W[c][kb+k]-W[y][kb+k]
    __shared__ float Psum[32][C_CLS]; //  8 KB : per-(a-group) partial S

    const int t  = threadIdx.x;
    const int y  = blockIdx.x >> 3;          // blockIdx / KCHUNK
    const int kc = blockIdx.x & 7;           // k-chunk index
    const int kb = kc * BK;                  // b-range start

    // ---- stage Vt: rows kb..kb+BK-1 of CV[y] (contiguous 32 KB, coalesced) ----
    {
        const float4* src = (const float4*)(CV + ((size_t)y * A_DIM * A_DIM
                                                  + (size_t)kb * A_DIM));
        float4* vdst = (float4*)&Vt[0][0];
        #pragma unroll
        for (int i = 0; i < (BK * A_DIM / 4) / 256; ++i)
            vdst[t + i * 256] = src[t + i * 256];
    }

    // ---- stage Dt (transposed diff chunk) ----
    {
        const int kq    = (t & 7) * 4;   // k = kq..kq+3
        const int chalf = t >> 3;        // 0..31
        const float4 wy = *(const float4*)(W + y * A_DIM + kb + kq);
        #pragma unroll
        for (int cc = 0; cc < 2; ++cc) {
            const int c = chalf + cc * 32;
            const float4 wc = *(const float4*)(W + c * A_DIM + kb + kq);
            Dt[kq + 0][c] = wc.x - wy.x;
            Dt[kq + 1][c] = wc.y - wy.y;
            Dt[kq + 2][c] = wc.z - wy.z;
            Dt[kq + 3][c] = wc.w - wy.w;
        }
    }
    __syncthreads();

    // ---- 8x8 register tile: c0=(t%8)*8 covers 64 c, a0=(t/8)*8 covers 256 a ----
    const int c0 = (t & 7) * 8;
    const int a0 = (t >> 3) * 8;
    float acc[8][8];
    #pragma unroll
    for (int i = 0; i < 8; ++i)
        #pragma unroll
        for (int j = 0; j < 8; ++j) acc[i][j] = 0.0f;

    #pragma unroll 2
    for (int k = 0; k < BK; ++k) {
        const float4 a_lo = *(const float4*)&Vt[k][a0];
        const float4 a_hi = *(const float4*)&Vt[k][a0 + 4];
        const float4 d_lo = *(const float4*)&Dt[k][c0];
        const float4 d_hi = *(const float4*)&Dt[k][c0 + 4];
        const float af[8] = {a_lo.x, a_lo.y, a_lo.z, a_lo.w,
                             a_hi.x, a_hi.y, a_hi.z, a_hi.w};
        const float df[8] = {d_lo.x, d_lo.y, d_lo.z, d_lo.w,
                             d_hi.x, d_hi.y, d_hi.z, d_hi.w};
        #pragma unroll
        for (int i = 0; i < 8; ++i)
            #pragma unroll
            for (int j = 0; j < 8; ++j)
                acc[i][j] += df[i] * af[j];
    }

    // ---- fused epilogue: s_i = sum_j acc[i][j] * (W[c0+i][a0+j] - W[y][a0+j]) ----
    float s[8];
    {
        const float4 wy_lo = *(const float4*)(W + y * A_DIM + a0);
        const float4 wy_hi = *(const float4*)(W + y * A_DIM + a0 + 4);
        const float wyv[8] = {wy_lo.x, wy_lo.y, wy_lo.z, wy_lo.w,
                              wy_hi.x, wy_hi.y, wy_hi.z, wy_hi.w};
        #pragma unroll
        for (int i = 0; i < 8; ++i) {
            const int c = c0 + i;
            const float4 wc_lo = *(const float4*)(W + c * A_DIM + a0);
            const float4 wc_hi = *(const float4*)(W + c * A_DIM + a0 + 4);
            const float wcv[8] = {wc_lo.x, wc_lo.y, wc_lo.z, wc_lo.w,
                                  wc_hi.x, wc_hi.y, wc_hi.z, wc_hi.w};
            float ss = 0.0f;
            #pragma unroll
            for (int j = 0; j < 8; ++j)
                ss += acc[i][j] * (wcv[j] - wyv[j]);
            s[i] = ss;
        }
    }
    // conflict-free staging: 8 consecutive floats per thread (2x ds_write_b128)
    const int ag = t >> 3;   // a-group 0..31
    *(float4*)&Psum[ag][c0]     = make_float4(s[0], s[1], s[2], s[3]);
    *(float4*)&Psum[ag][c0 + 4] = make_float4(s[4], s[5], s[6], s[7]);
    __syncthreads();

    if (t < C_CLS) {
        float r = 0.0f;
        #pragma unroll
        for (int g = 0; g < 32; ++g) r += Psum[g][t];   // stride-1 across lanes
        Spart[(size_t)kc * C_CLS * C_CLS + y * C_CLS + t] = r;
    }
}

// ---------------------------------------------------------------------------
// Kernel B: per-row softmax CE on aug = pred + 0.5*Lambda*sum_k Spart[k][y].
// One wave per row, 4 waves/block, 4 rows per wave; per-block partial to ws.
// ---------------------------------------------------------------------------
__global__ __launch_bounds__(256) void loss_kernel(
    const float* __restrict__ pred,    // [N][C]
    const int*   __restrict__ labels,  // [N]
    const float* __restrict__ lambda_p,
    const float* __restrict__ Spart,   // [KCHUNK][C][C]
    float* __restrict__ partials)      // [LOSS_BLOCKS]
{
    __shared__ float wsum[4];
    const int t    = threadIdx.x;
    const int lane = t & 63;
    const int wgid = blockIdx.x * 4 + (t >> 6);   // global wave id, 0..1023
    const float lam = 0.5f * lambda_p[0];

    float acc_nll = 0.0f;
    #pragma unroll
    for (int r = 0; r < 4; ++r) {
        const int n = r * 1024 + wgid;
        const int y = labels[n];
        float sp = 0.0f;
        #pragma unroll
        for (int k = 0; k < KCHUNK; ++k)
            sp += Spart[(size_t)k * C_CLS * C_CLS + y * C_CLS + lane];
        const float logit = pred[n * C_CLS + lane] + lam * sp;

        float m = logit;
        #pragma unroll
        for (int off = 32; off > 0; off >>= 1)
            m = fmaxf(m, __shfl_xor(m, off, 64));
        float e = __expf(logit - m);
        float ssum = e;
        #pragma unroll
        for (int off = 32; off > 0; off >>= 1)
            ssum += __shfl_xor(ssum, off, 64);
        const float ly = __shfl(logit, y, 64);
        acc_nll += logf(ssum) + m - ly;
    }

    if (lane == 0) wsum[t >> 6] = acc_nll;
    __syncthreads();
    if (t == 0)
        partials[blockIdx.x] = wsum[0] + wsum[1] + wsum[2] + wsum[3];
}

// ---------------------------------------------------------------------------
// Kernel C: reduce 256 block partials -> mean loss. One block.
// ---------------------------------------------------------------------------
__global__ __launch_bounds__(256) void finalize_kernel(
    const float* __restrict__ partials, float* __restrict__ out)
{
    __shared__ float wsum[4];
    const int t = threadIdx.x;
    float v = partials[t];
    #pragma unroll
    for (int off = 32; off > 0; off >>= 1)
        v += __shfl_xor(v, off, 64);
    if ((t & 63) == 0) wsum[t >> 6] = v;
    __syncthreads();
    if (t == 0)
        out[0] = (wsum[0] + wsum[1] + wsum[2] + wsum[3]) * (1.0f / (float)N_ROWS);
}

// ---------------------------------------------------------------------------
extern "C" void kernel_launch(void* const* d_in, const int* in_sizes, int n_in,
                              void* d_out, int out_size, void* d_ws, size_t ws_size,
                              hipStream_t stream) {
    (void)in_sizes; (void)n_in; (void)out_size; (void)ws_size;
    const float* W      = (const float*)d_in[0];   // fc_weight [64][256]
    // d_in[1] = features (unused by the reference computation)
    const float* pred   = (const float*)d_in[2];   // [4096][64]
    const int*   labels = (const int*)d_in[3];     // [4096]
    const float* lam    = (const float*)d_in[4];   // scalar
    const float* CV     = (const float*)d_in[5];   // [64][256][256]
    float* out = (float*)d_out;

    float* Spart    = (float*)d_ws;                             // 8*64*64 floats = 128 KB
    float* partials = (float*)d_ws + KCHUNK * C_CLS * C_CLS;    // 256 floats

    qform_kernel<<<dim3(C_CLS * KCHUNK), dim3(256), 0, stream>>>(W, CV, Spart);
    loss_kernel<<<dim3(LOSS_BLOCKS), dim3(256), 0, stream>>>(pred, labels, lam, Spart, partials);
    finalize_kernel<<<dim3(1), dim3(256), 0, stream>>>(partials, out);
}